// Round 11
// baseline (1182.422 us; speedup 1.0000x reference)
//
#include <hip/hip_runtime.h>
#include <math.h>

// Problem constants
#define NN 50000
#define NE 800000

typedef __attribute__((ext_vector_type(8))) short  short8;   // 8 bf16 (4 VGPRs)
typedef __attribute__((ext_vector_type(4))) short  short4v;  // 4 bf16 (2 VGPRs)
typedef __attribute__((ext_vector_type(4))) float  floatx4;  // MFMA acc

// bf16 bits <-> float helpers
__device__ __forceinline__ float bf2f(unsigned short u) {
    union { unsigned int i; float f; } v; v.i = ((unsigned int)u) << 16; return v.f;
}
__device__ __forceinline__ unsigned short f2bf(float f) {
    union { float f; unsigned int i; } v; v.f = f;
    unsigned int i = v.i;
    i += 0x7FFFu + ((i >> 16) & 1u);   // round to nearest even
    return (unsigned short)(i >> 16);
}

__device__ __forceinline__ void storeF(float* p, float v)          { *p = v; }
__device__ __forceinline__ void storeF(unsigned short* p, float v) { *p = f2bf(v); }

__device__ __forceinline__ float leaky(float v) { return (v > 0.f) ? v : 0.2f * v; }
__device__ __forceinline__ float ntldf(const float* p) { return __builtin_nontemporal_load(p); }

// async 16B global -> LDS (gfx950 global_load_lds_dwordx4)
__device__ __forceinline__ void gload_lds16(const unsigned short* g, unsigned short* l) {
    __builtin_amdgcn_global_load_lds(
        (const __attribute__((address_space(1))) unsigned int*)g,
        (__attribute__((address_space(3))) unsigned int*)l, 16, 0, 0);
}

// ---------------------------------------------------------------------------
// CSR build
// ---------------------------------------------------------------------------
__global__ void deg_kernel(const int* __restrict__ edges, int* __restrict__ deg, int E) {
    int e = blockIdx.x * blockDim.x + threadIdx.x;
    if (e < E) atomicAdd(&deg[edges[2 * e + 1]], 1);
}

__global__ void scan_kernel(const int* __restrict__ deg, int* __restrict__ row_ptr,
                            int* __restrict__ cursor, int n) {
    __shared__ int sums[256];
    int t = threadIdx.x;
    const int C = (n + 255) / 256;
    int lo = t * C, hi = min(lo + C, n);
    if (lo > n) lo = n;
    if (hi < lo) hi = lo;
    int s = 0;
    for (int i = lo; i < hi; ++i) s += deg[i];
    sums[t] = s;
    __syncthreads();
    for (int off = 1; off < 256; off <<= 1) {
        int v = (t >= off) ? sums[t - off] : 0;
        __syncthreads();
        sums[t] += v;
        __syncthreads();
    }
    int run = (t == 0) ? 0 : sums[t - 1];
    for (int i = lo; i < hi; ++i) {
        int d = deg[i];
        row_ptr[i] = run;
        cursor[i]  = run;
        run += d;
    }
    if (t == 255) row_ptr[n] = sums[255];
}

__global__ void scatter_kernel(const int* __restrict__ edges, int* __restrict__ cursor,
                               int* __restrict__ edge_src, int* __restrict__ edge_dst, int E) {
    int e = blockIdx.x * blockDim.x + threadIdx.x;
    if (e < E) {
        int sv = edges[2 * e], d = edges[2 * e + 1];
        int pos = atomicAdd(&cursor[d], 1);
        if (pos >= 0 && pos < E) { edge_src[pos] = sv; edge_dst[pos] = d; }
    }
}

// ---------------------------------------------------------------------------
// Per-edge softmax weight precompute: pw[e*H+h] = exp(leaky(e_s+e_d))
// ---------------------------------------------------------------------------
template <int H>
__global__ __launch_bounds__(256) void pw_kernel(const float* __restrict__ e_s,
                                                 const float* __restrict__ e_d,
                                                 const int* __restrict__ esrc,
                                                 const int* __restrict__ edst,
                                                 float* __restrict__ pw, int E) {
    int e = blockIdx.x * blockDim.x + threadIdx.x;
    if (e >= E) return;
    int s = esrc[e], d = edst[e];
    const float* ps = e_s + (size_t)s * H;
    const float* pd = e_d + (size_t)d * H;
#pragma unroll
    for (int h = 0; h < H; ++h)
        pw[(size_t)e * H + h] = __expf(leaky(ps[h] + pd[h]));
}

// ---------------------------------------------------------------------------
// Weight prep: fp32 W[K][N] -> bf16 BT[Npad][K];  x0 fp32 -> bf16
// ---------------------------------------------------------------------------
__global__ void transpose_w(const float* __restrict__ W, unsigned short* __restrict__ BT,
                            int K, int N, int Npad) {
    int idx = blockIdx.x * blockDim.x + threadIdx.x;
    if (idx >= Npad * K) return;
    int n = idx / K, k = idx - n * K;
    float v = (n < N) ? W[(size_t)k * N + n] : 0.f;
    BT[idx] = f2bf(v);
}

__global__ __launch_bounds__(256) void f32_to_bf16(const float* __restrict__ in,
                                                   unsigned short* __restrict__ out, int n4) {
    int i = (blockIdx.x * blockDim.x + threadIdx.x) * 4;
    if (i + 3 < n4) {
        float4 v = *(const float4*)(in + i);
        ushort4 o;
        o.x = f2bf(v.x); o.y = f2bf(v.y); o.z = f2bf(v.z); o.w = f2bf(v.w);
        *(ushort4*)(out + i) = o;
    }
}

// ---------------------------------------------------------------------------
// MFMA bf16 GEMM with async global->LDS staging (m97 recipe).
// ---------------------------------------------------------------------------
template <typename TC>
__global__ __launch_bounds__(256) void gemm_mfma(const unsigned short* __restrict__ A,
                                                 const unsigned short* __restrict__ BT,
                                                 TC* __restrict__ C,
                                                 int M, int K, int NS, int Ncheck) {
    __shared__ __align__(16) unsigned short As[128 * 32];
    __shared__ __align__(16) unsigned short Bs[128 * 32];

    const int t    = threadIdx.x;
    const int wave = t >> 6, lane = t & 63;
    const int wm   = (wave >> 1) * 64, wn = (wave & 1) * 64;
    const int l15  = lane & 15, q = lane >> 4;
    const int row0 = blockIdx.y * 128, col0 = blockIdx.x * 128;

    floatx4 acc[4][4];
#pragma unroll
    for (int i = 0; i < 4; ++i)
#pragma unroll
        for (int j = 0; j < 4; ++j) acc[i][j] = (floatx4){0.f, 0.f, 0.f, 0.f};

    for (int k0 = 0; k0 < K; k0 += 32) {
#pragma unroll
        for (int p = 0; p < 2; ++p) {
            int idx = p * 256 + t;
            int r = idx >> 2, qq = idx & 3;
            int ar = row0 + r; ar = (ar < M) ? ar : (M - 1);
            unsigned short* ldsA = As + (p * 2048 + wave * 512);
            unsigned short* ldsB = Bs + (p * 2048 + wave * 512);
            gload_lds16(A  + (size_t)ar * K + k0 + qq * 8, ldsA);
            gload_lds16(BT + (size_t)(col0 + r) * K + k0 + qq * 8, ldsB);
        }
        __syncthreads();

        short8 af[4], bfr[4];
#pragma unroll
        for (int mi = 0; mi < 4; ++mi) af[mi]  = *(const short8*)&As[(wm + 16 * mi + l15) * 32 + q * 8];
#pragma unroll
        for (int ni = 0; ni < 4; ++ni) bfr[ni] = *(const short8*)&Bs[(wn + 16 * ni + l15) * 32 + q * 8];
#pragma unroll
        for (int mi = 0; mi < 4; ++mi)
#pragma unroll
            for (int ni = 0; ni < 4; ++ni)
                acc[mi][ni] = __builtin_amdgcn_mfma_f32_16x16x32_bf16(af[mi], bfr[ni], acc[mi][ni], 0, 0, 0);
        __syncthreads();
    }

#pragma unroll
    for (int ni = 0; ni < 4; ++ni) {
        int gc = col0 + wn + 16 * ni + l15;
        if (gc >= Ncheck) continue;
#pragma unroll
        for (int mi = 0; mi < 4; ++mi) {
#pragma unroll
            for (int r = 0; r < 4; ++r) {
                int gr = row0 + wm + 16 * mi + q * 4 + r;
                if (gr < M) storeF(C + (size_t)gr * NS + gc, acc[mi][ni][r]);
            }
        }
    }
}

// ---------------------------------------------------------------------------
// escore, H=4 U=128. 4 nodes/block, one wave each.
// ---------------------------------------------------------------------------
__global__ __launch_bounds__(256) void escore4(const unsigned short* __restrict__ hbuf,
                                               const float* __restrict__ a_src,
                                               const float* __restrict__ a_dst,
                                               float* __restrict__ e_s,
                                               float* __restrict__ e_d) {
    const int wave = threadIdx.x >> 6, lane = threadIdx.x & 63;
    const int n = blockIdx.x * 4 + wave;
    const int h = lane >> 4, seg = lane & 15;

    short8 hv = *(const short8*)(hbuf + (size_t)n * 512 + lane * 8);
    float4 as0 = *(const float4*)(a_src + lane * 8);
    float4 as1 = *(const float4*)(a_src + lane * 8 + 4);
    float4 ad0 = *(const float4*)(a_dst + lane * 8);
    float4 ad1 = *(const float4*)(a_dst + lane * 8 + 4);
    float av[8] = {as0.x, as0.y, as0.z, as0.w, as1.x, as1.y, as1.z, as1.w};
    float dv[8] = {ad0.x, ad0.y, ad0.z, ad0.w, ad1.x, ad1.y, ad1.z, ad1.w};

    float ps = 0.f, pd = 0.f;
#pragma unroll
    for (int j = 0; j < 8; ++j) {
        float x = bf2f((unsigned short)hv[j]);
        ps = fmaf(x, av[j], ps);
        pd = fmaf(x, dv[j], pd);
    }
#pragma unroll
    for (int off = 1; off < 16; off <<= 1) {
        ps += __shfl_xor(ps, off);
        pd += __shfl_xor(pd, off);
    }
    if (seg == 0) {
        e_s[(size_t)n * 4 + h] = ps;
        e_d[(size_t)n * 4 + h] = pd;
    }
}

// ---------------------------------------------------------------------------
// escore, H=6 U=121 (stride 728). 4 nodes/block, segmented LDS-atomic reduce.
// ---------------------------------------------------------------------------
__global__ __launch_bounds__(256) void escore6(const unsigned short* __restrict__ hbuf,
                                               const float* __restrict__ a_src,
                                               const float* __restrict__ a_dst,
                                               float* __restrict__ e_s,
                                               float* __restrict__ e_d) {
    __shared__ float red[4][6][2];
    const int wave = threadIdx.x >> 6, lane = threadIdx.x & 63;
    const int n = blockIdx.x * 4 + wave;

    if (lane < 12) red[wave][lane >> 1][lane & 1] = 0.f;
    __syncthreads();

    const int f0 = lane * 8;
    const int hA0 = f0 / 121;
    int cut0 = (hA0 + 1) * 121 - f0; cut0 = (cut0 > 8) ? 8 : cut0;
    const int hB0 = (cut0 < 8) ? (hA0 + 1) : hA0;
    {
        short8 hv = *(const short8*)(hbuf + (size_t)n * 728 + f0);
        float psA = 0.f, pdA = 0.f, psB = 0.f, pdB = 0.f;
#pragma unroll
        for (int j = 0; j < 8; ++j) {
            float x = bf2f((unsigned short)hv[j]);
            float a = a_src[f0 + j], d = a_dst[f0 + j];
            if (j < cut0) { psA = fmaf(x, a, psA); pdA = fmaf(x, d, pdA); }
            else          { psB = fmaf(x, a, psB); pdB = fmaf(x, d, pdB); }
        }
        atomicAdd(&red[wave][hA0][0], psA);
        atomicAdd(&red[wave][hA0][1], pdA);
        if (cut0 < 8) {
            atomicAdd(&red[wave][hB0][0], psB);
            atomicAdd(&red[wave][hB0][1], pdB);
        }
    }
    const int f1 = 512 + lane * 8;
    if (f1 < 728) {
        const int hA1 = (f1 < 726) ? (f1 / 121) : 5;
        int cut1 = (hA1 + 1) * 121 - f1; cut1 = (cut1 > 8) ? 8 : (cut1 < 0 ? 0 : cut1);
        const int hB1 = (cut1 < 8) ? min(hA1 + 1, 5) : hA1;
        short8 hv = *(const short8*)(hbuf + (size_t)n * 728 + f1);
        float psA = 0.f, pdA = 0.f, psB = 0.f, pdB = 0.f;
#pragma unroll
        for (int j = 0; j < 8; ++j) {
            if (f1 + j >= 726) continue;
            float x = bf2f((unsigned short)hv[j]);
            float a = a_src[f1 + j], d = a_dst[f1 + j];
            if (j < cut1) { psA = fmaf(x, a, psA); pdA = fmaf(x, d, pdA); }
            else          { psB = fmaf(x, a, psB); pdB = fmaf(x, d, pdB); }
        }
        atomicAdd(&red[wave][hA1][0], psA);
        atomicAdd(&red[wave][hA1][1], pdA);
        if (cut1 < 8) {
            atomicAdd(&red[wave][hB1][0], psB);
            atomicAdd(&red[wave][hB1][1], pdB);
        }
    }
    __syncthreads();
    if (lane < 6) {
        e_s[(size_t)n * 6 + lane] = red[wave][lane][0];
        e_d[(size_t)n * 6 + lane] = red[wave][lane][1];
    }
}

// ---------------------------------------------------------------------------
// agg D=512, phase PH covers features [PH*256, PH*256+256).
// Lane owns 4 features (one head); 8 B gathers, 8-edge pipeline.
// den recomputed per phase (bitwise identical). Working set 25.6 MB -> L3.
// ---------------------------------------------------------------------------
template <int PH>
__global__ __launch_bounds__(256) void agg_w512_ph(const unsigned short* __restrict__ hbuf,
                                                   const float* __restrict__ pw,
                                                   const int* __restrict__ rowp,
                                                   const int* __restrict__ esrc,
                                                   const unsigned short* res,
                                                   unsigned short* out) {
    const int wave = threadIdx.x >> 6, lane = threadIdx.x & 63;
    const int n = blockIdx.x * 4 + wave;      // grid*4 == NN
    const int f = PH * 256 + lane * 4;
    const int h = f >> 7;
    const int beg = rowp[n], end = rowp[n + 1];

    float den = 0.f;
    float acc[4] = {0.f, 0.f, 0.f, 0.f};

    int e = beg;
    for (; e + 8 <= end; e += 8) {
        int s[8];
        float p[8];
        short4v r[8];
#pragma unroll
        for (int k = 0; k < 8; ++k) s[k] = esrc[e + k];
#pragma unroll
        for (int k = 0; k < 8; ++k) p[k] = ntldf(pw + (size_t)(e + k) * 4 + h);
#pragma unroll
        for (int k = 0; k < 8; ++k) r[k] = *(const short4v*)(hbuf + (size_t)s[k] * 512 + f);
#pragma unroll
        for (int k = 0; k < 8; ++k) den += p[k];
#pragma unroll
        for (int j = 0; j < 4; ++j) {
            float a = acc[j];
#pragma unroll
            for (int k = 0; k < 8; ++k) a = fmaf(p[k], bf2f((unsigned short)r[k][j]), a);
            acc[j] = a;
        }
    }
    for (; e < end; ++e) {
        int s0 = esrc[e];
        float p0 = ntldf(pw + (size_t)e * 4 + h);
        short4v r0 = *(const short4v*)(hbuf + (size_t)s0 * 512 + f);
        den += p0;
#pragma unroll
        for (int j = 0; j < 4; ++j) acc[j] = fmaf(p0, bf2f((unsigned short)r0[j]), acc[j]);
    }

    const float inv = 1.f / fmaxf(den, 1e-9f);
    short4v rv = *(const short4v*)(res + (size_t)n * 512 + f);
    short4v ov;
#pragma unroll
    for (int j = 0; j < 4; ++j) {
        float z = acc[j] * inv + bf2f((unsigned short)rv[j]);
        z = (z > 0.f) ? z : (__expf(z) - 1.f);   // elu
        ov[j] = (short)f2bf(z);
    }
    *(short4v*)(out + (size_t)n * 512 + f) = ov;
}

// ---------------------------------------------------------------------------
// agg layer 3 phase 0: features [0,512) (heads 0..3 full + head 4 partial).
// Writes out = res + (1/6) * (sum of phase-0 head vals). Working set 51 MB.
// ---------------------------------------------------------------------------
__global__ __launch_bounds__(256) void agg_w726_ph0(const unsigned short* __restrict__ hbuf,
                                                    const float* __restrict__ pw,
                                                    const int* __restrict__ rowp,
                                                    const int* __restrict__ esrc,
                                                    const float* res,
                                                    float* out) {
    __shared__ float s_vals[4][512];
    const int wave = threadIdx.x >> 6, lane = threadIdx.x & 63;
    const int n = blockIdx.x * 4 + wave;
    const int beg = rowp[n], end = rowp[n + 1];

    const int f0 = lane * 8;
    const int hA = f0 / 121;
    int cut = (hA + 1) * 121 - f0; cut = (cut > 8) ? 8 : cut;
    const int hB = (cut < 8) ? (hA + 1) : hA;   // <= 4 since f0+8 <= 512

    float dA = 0.f, dB = 0.f;
    float acc[8];
#pragma unroll
    for (int j = 0; j < 8; ++j) acc[j] = 0.f;

    int e = beg;
    for (; e + 4 <= end; e += 4) {
        int s[4];
#pragma unroll
        for (int k = 0; k < 4; ++k) s[k] = esrc[e + k];
        float pA[4], pB[4];
#pragma unroll
        for (int k = 0; k < 4; ++k) {
            const float* q = pw + (size_t)(e + k) * 6;
            pA[k] = ntldf(q + hA);
            pB[k] = ntldf(q + hB);
        }
        short8 r[4];
#pragma unroll
        for (int k = 0; k < 4; ++k) r[k] = *(const short8*)(hbuf + (size_t)s[k] * 728 + f0);
#pragma unroll
        for (int k = 0; k < 4; ++k) { dA += pA[k]; dB += pB[k]; }
#pragma unroll
        for (int j = 0; j < 8; ++j) {
            float a = acc[j];
#pragma unroll
            for (int k = 0; k < 4; ++k)
                a = fmaf((j < cut) ? pA[k] : pB[k], bf2f((unsigned short)r[k][j]), a);
            acc[j] = a;
        }
    }
    for (; e < end; ++e) {
        int s = esrc[e];
        const float* q = pw + (size_t)e * 6;
        float pA = ntldf(q + hA), pB = ntldf(q + hB);
        short8 r = *(const short8*)(hbuf + (size_t)s * 728 + f0);
        dA += pA; dB += pB;
#pragma unroll
        for (int j = 0; j < 8; ++j)
            acc[j] = fmaf((j < cut) ? pA : pB, bf2f((unsigned short)r[j]), acc[j]);
    }

    const float iA = 1.f / fmaxf(dA, 1e-9f), iB = 1.f / fmaxf(dB, 1e-9f);
#pragma unroll
    for (int j = 0; j < 8; ++j) s_vals[wave][f0 + j] = acc[j] * ((j < cut) ? iA : iB);
    __syncthreads();

    // out = res + (1/6) * (heads 0..3 full + head4 features 484..511 (u<28))
    for (int u = lane; u < 121; u += 64) {
        float sum = s_vals[wave][u] + s_vals[wave][121 + u]
                  + s_vals[wave][242 + u] + s_vals[wave][363 + u];
        if (u < 28) sum += s_vals[wave][484 + u];
        out[(size_t)n * 121 + u] = sum * (1.f / 6.f) + res[(size_t)n * 121 + u];
    }
}

// ---------------------------------------------------------------------------
// agg layer 3 phase 1: features [512,728) (head 4 tail + head 5).
// Adds (1/6) * (phase-1 head vals) into out (stream-ordered after phase 0).
// Working set ~25 MB. Lane owns 4 features (fi = lane*4 < 216).
// ---------------------------------------------------------------------------
__global__ __launch_bounds__(256) void agg_w726_ph1(const unsigned short* __restrict__ hbuf,
                                                    const float* __restrict__ pw,
                                                    const int* __restrict__ rowp,
                                                    const int* __restrict__ esrc,
                                                    float* out) {
    __shared__ float s_vals[4][216];
    const int wave = threadIdx.x >> 6, lane = threadIdx.x & 63;
    const int n = blockIdx.x * 4 + wave;
    const int beg = rowp[n], end = rowp[n + 1];

    const int fi = lane * 4;           // within [0,256); active if < 216
    const bool active = (fi < 216);
    const int f = 512 + fi;            // global feature
    const int hA = active ? min(f / 121, 5) : 5;
    int cut = (hA + 1) * 121 - f; cut = (cut > 4) ? 4 : (cut < 0 ? 0 : cut);
    const int hB = (cut < 4) ? min(hA + 1, 5) : hA;

    float dA = 0.f, dB = 0.f;
    float acc[4] = {0.f, 0.f, 0.f, 0.f};

    if (active) {
        int e = beg;
        for (; e + 4 <= end; e += 4) {
            int s[4];
#pragma unroll
            for (int k = 0; k < 4; ++k) s[k] = esrc[e + k];
            float pA[4], pB[4];
#pragma unroll
            for (int k = 0; k < 4; ++k) {
                const float* q = pw + (size_t)(e + k) * 6;
                pA[k] = ntldf(q + hA);
                pB[k] = ntldf(q + hB);
            }
            short4v r[4];
#pragma unroll
            for (int k = 0; k < 4; ++k) r[k] = *(const short4v*)(hbuf + (size_t)s[k] * 728 + f);
#pragma unroll
            for (int k = 0; k < 4; ++k) { dA += pA[k]; dB += pB[k]; }
#pragma unroll
            for (int j = 0; j < 4; ++j) {
                float a = acc[j];
#pragma unroll
                for (int k = 0; k < 4; ++k)
                    a = fmaf((j < cut) ? pA[k] : pB[k], bf2f((unsigned short)r[k][j]), a);
                acc[j] = a;
            }
        }
        for (; e < end; ++e) {
            int s = esrc[e];
            const float* q = pw + (size_t)e * 6;
            float pA = ntldf(q + hA), pB = ntldf(q + hB);
            short4v r = *(const short4v*)(hbuf + (size_t)s * 728 + f);
            dA += pA; dB += pB;
#pragma unroll
            for (int j = 0; j < 4; ++j)
                acc[j] = fmaf((j < cut) ? pA : pB, bf2f((unsigned short)r[j]), acc[j]);
        }

        const float iA = 1.f / fmaxf(dA, 1e-9f), iB = 1.f / fmaxf(dB, 1e-9f);
#pragma unroll
        for (int j = 0; j < 4; ++j)
            s_vals[wave][fi + j] = acc[j] * ((j < cut) ? iA : iB);
    }
    __syncthreads();

    // out += (1/6) * (head4 features 512..604 (u>=28) + head5 605..725)
    for (int u = lane; u < 121; u += 64) {
        float add = s_vals[wave][93 + u];                 // head 5 (f=605+u)
        if (u >= 28) add += s_vals[wave][u - 28];         // head 4 (f=484+u>=512)
        size_t idx = (size_t)n * 121 + u;
        out[idx] = out[idx] + add * (1.f / 6.f);
    }
}

// ---------------------------------------------------------------------------
// Launch
// ---------------------------------------------------------------------------
static inline size_t align256(size_t x) { return (x + 255) & ~(size_t)255; }

extern "C" void kernel_launch(void* const* d_in, const int* in_sizes, int n_in,
                              void* d_out, int out_size, void* d_ws, size_t ws_size,
                              hipStream_t stream) {
    const float* x0  = (const float*)d_in[0];   // [50000,128] fp32
    const int* edges = (const int*)d_in[1];     // [800000,2] int32
    const float* W1  = (const float*)d_in[2];   // [128,512]
    const float* a1s = (const float*)d_in[3];
    const float* a1d = (const float*)d_in[4];
    const float* R1  = (const float*)d_in[5];   // [128,512]
    const float* W2  = (const float*)d_in[6];   // [512,512]
    const float* a2s = (const float*)d_in[7];
    const float* a2d = (const float*)d_in[8];
    const float* W3  = (const float*)d_in[9];   // [512,726]
    const float* a3s = (const float*)d_in[10];
    const float* a3d = (const float*)d_in[11];
    const float* R3  = (const float*)d_in[12];  // [512,121]
    float* out = (float*)d_out;                 // [50000,121] fp32

    // workspace carve (~155 MB; proven safe rounds 8-10)
    char* w = (char*)d_ws;
    size_t off = 0;
    unsigned short* hbuf = (unsigned short*)(w + off); off = align256(off + (size_t)NN * 728 * 2);
    unsigned short* x1   = (unsigned short*)(w + off); off = align256(off + (size_t)NN * 512 * 2);
    float* es  = (float*)(w + off); off = align256(off + (size_t)NN * 6 * 4);
    float* ed  = (float*)(w + off); off = align256(off + (size_t)NN * 6 * 4);
    int* rowp  = (int*)(w + off);   off = align256(off + (size_t)(NN + 1) * 4);
    int* esrc  = (int*)(w + off);   off = align256(off + (size_t)NE * 4);
    int* edst  = (int*)(w + off);   off = align256(off + (size_t)NE * 4);
    float* pw  = (float*)(w + off); off = align256(off + (size_t)NE * 6 * 4 + 256);
    unsigned short* w1t = (unsigned short*)(w + off); off = align256(off + (size_t)512 * 128 * 2);
    unsigned short* r1t = (unsigned short*)(w + off); off = align256(off + (size_t)512 * 128 * 2);
    unsigned short* w2t = (unsigned short*)(w + off); off = align256(off + (size_t)512 * 512 * 2);
    unsigned short* w3t = (unsigned short*)(w + off); off = align256(off + (size_t)768 * 512 * 2);
    unsigned short* r3t = (unsigned short*)(w + off); off = align256(off + (size_t)128 * 512 * 2);
    int* deg = (int*)es;                     // overlay: dead after CSR build
    int* cur = (int*)ed;
    unsigned short* x0b = (unsigned short*)pw;   // overlay: dead before pw written
    (void)ws_size;

    const int EB = (NE + 255) / 256;
    const int MB = (NN + 127) / 128;   // 391
    const int AB = NN / 4;             // 12500 blocks, 4 waves each

    // --- CSR build ---
    hipMemsetAsync(deg, 0, (size_t)NN * 4, stream);
    deg_kernel<<<EB, 256, 0, stream>>>(edges, deg, NE);
    scan_kernel<<<1, 256, 0, stream>>>(deg, rowp, cur, NN);
    scatter_kernel<<<EB, 256, 0, stream>>>(edges, cur, esrc, edst, NE);

    // --- weight prep + x0 bf16 ---
    transpose_w<<<(512 * 128 + 255) / 256, 256, 0, stream>>>(W1, w1t, 128, 512, 512);
    transpose_w<<<(512 * 128 + 255) / 256, 256, 0, stream>>>(R1, r1t, 128, 512, 512);
    transpose_w<<<(512 * 512 + 255) / 256, 256, 0, stream>>>(W2, w2t, 512, 512, 512);
    transpose_w<<<(768 * 512 + 255) / 256, 256, 0, stream>>>(W3, w3t, 512, 726, 768);
    transpose_w<<<(128 * 512 + 255) / 256, 256, 0, stream>>>(R3, r3t, 512, 121, 128);
    f32_to_bf16<<<(NN * 128 / 4 + 255) / 256, 256, 0, stream>>>(x0, x0b, NN * 128);

    // --- Layer 1: 128 -> 4x128 concat, res = x0 @ R1, elu ---
    gemm_mfma<<<dim3(4, MB), 256, 0, stream>>>(x0b, w1t, hbuf, NN, 128, 512, 512);
    gemm_mfma<<<dim3(4, MB), 256, 0, stream>>>(x0b, r1t, x1,   NN, 128, 512, 512);
    escore4<<<AB, 256, 0, stream>>>(hbuf, a1s, a1d, es, ed);
    pw_kernel<4><<<EB, 256, 0, stream>>>(es, ed, esrc, edst, pw, NE);   // pw overwrites x0b (dead)
    agg_w512_ph<0><<<AB, 256, 0, stream>>>(hbuf, pw, rowp, esrc, x1, x1);
    agg_w512_ph<1><<<AB, 256, 0, stream>>>(hbuf, pw, rowp, esrc, x1, x1);

    // --- Layer 2: 512 -> 4x128 concat, res = identity(x1), elu (in place) ---
    gemm_mfma<<<dim3(4, MB), 256, 0, stream>>>(x1, w2t, hbuf, NN, 512, 512, 512);
    escore4<<<AB, 256, 0, stream>>>(hbuf, a2s, a2d, es, ed);
    pw_kernel<4><<<EB, 256, 0, stream>>>(es, ed, esrc, edst, pw, NE);
    agg_w512_ph<0><<<AB, 256, 0, stream>>>(hbuf, pw, rowp, esrc, x1, x1);
    agg_w512_ph<1><<<AB, 256, 0, stream>>>(hbuf, pw, rowp, esrc, x1, x1);

    // --- Layer 3: 512 -> 6x121 avg, res = x1 @ R3 (fp32 -> d_out), identity ---
    gemm_mfma<<<dim3(6, MB), 256, 0, stream>>>(x1, w3t, hbuf, NN, 512, 728, 726);
    gemm_mfma<<<dim3(1, MB), 256, 0, stream>>>(x1, r3t, out,  NN, 512, 121, 121);
    escore6<<<AB, 256, 0, stream>>>(hbuf, a3s, a3d, es, ed);
    pw_kernel<6><<<EB, 256, 0, stream>>>(es, ed, esrc, edst, pw, NE);
    agg_w726_ph0<<<AB, 256, 0, stream>>>(hbuf, pw, rowp, esrc, out, out);
    agg_w726_ph1<<<AB, 256, 0, stream>>>(hbuf, pw, rowp, esrc, out);
}